// Round 1
// baseline (398.873 us; speedup 1.0000x reference)
//
#include <hip/hip_runtime.h>
#include <hip/hip_bf16.h>

typedef float f32x4 __attribute__((ext_vector_type(4)));
typedef short s16x8 __attribute__((ext_vector_type(8)));
typedef unsigned short u16;
typedef unsigned short u16x8 __attribute__((ext_vector_type(8)));
typedef unsigned short u16x4 __attribute__((ext_vector_type(4)));

#define MROWS 4096   // B*S
#define NQKV  3072   // NH*HD + 2*NKV*HD
#define DMODEL 2048

__device__ __forceinline__ u16 f2bf(float f) {
  __hip_bfloat16 h = __float2bfloat16(f);
  return __builtin_bit_cast(u16, h);
}
__device__ __forceinline__ float bf2f(u16 u) {
  __hip_bfloat16 h = __builtin_bit_cast(__hip_bfloat16, u);
  return __bfloat162float(h);
}

// ---------------- fp32 -> bf16 convert (x) ----------------
__global__ __launch_bounds__(256) void k_conv_x(const float* __restrict__ x, u16* __restrict__ o) {
  size_t i = ((size_t)blockIdx.x * 256 + threadIdx.x) * 4;
  float4 v = *(const float4*)(x + i);
  u16x4 r = { f2bf(v.x), f2bf(v.y), f2bf(v.z), f2bf(v.w) };
  *(u16x4*)(o + i) = r;
}

// ------- transpose + convert: src (K x N) f32 -> dst (N x K) bf16 -------
__global__ __launch_bounds__(256) void k_transw(const float* __restrict__ src, u16* __restrict__ dst,
                                                int N, int K) {
  __shared__ u16 t[64][68];
  int n0 = blockIdx.x * 64, k0 = blockIdx.y * 64;
  int tid = threadIdx.x;
#pragma unroll
  for (int r = 0; r < 4; ++r) {
    int k = r * 16 + (tid >> 4);
    int n = (tid & 15) * 4;
    float4 v = *(const float4*)(src + (size_t)(k0 + k) * N + n0 + n);
    t[n + 0][k] = f2bf(v.x);
    t[n + 1][k] = f2bf(v.y);
    t[n + 2][k] = f2bf(v.z);
    t[n + 3][k] = f2bf(v.w);
  }
  __syncthreads();
#pragma unroll
  for (int r = 0; r < 4; ++r) {
    int n = r * 16 + (tid >> 4);
    int k = (tid & 15) * 4;
    u16x4 o = { t[n][k], t[n][k + 1], t[n][k + 2], t[n][k + 3] };
    *(u16x4*)(dst + (size_t)(n0 + n) * K + k0 + k) = o;
  }
}

// ---------------- bf16 GEMM: C(MxN) = A(MxK) * Bt(NxK)^T ----------------
// 128x128 tile, BK=64, 4 waves (2x2), 16x16x32 MFMA, swizzled LDS.
template <typename OutT>
__global__ __launch_bounds__(256) void k_gemm(const u16* __restrict__ A, const u16* __restrict__ Bt,
                                              OutT* __restrict__ C, int M, int N, int K) {
  __shared__ char sA[128 * 128];  // 128 rows x 128B (64 bf16), XOR-swizzled
  __shared__ char sB[128 * 128];
  const int tid = threadIdx.x;
  const int l = tid & 63;
  const int m0 = blockIdx.y * 128, n0 = blockIdx.x * 128;
  const int wr = tid >> 7, wc = (tid >> 6) & 1;
  f32x4 acc[4][4] = {};
  const int nkt = K >> 6;
  for (int kt = 0; kt < nkt; ++kt) {
    __syncthreads();
#pragma unroll
    for (int c = 0; c < 4; ++c) {
      int p = c * 4096 + tid * 16;
      int row = p >> 7, cb = p & 127;
      u16x8 va = *(const u16x8*)(A + (size_t)(m0 + row) * K + kt * 64 + (cb >> 1));
      *(u16x8*)(sA + row * 128 + (cb ^ ((row & 7) << 4))) = va;
      u16x8 vb = *(const u16x8*)(Bt + (size_t)(n0 + row) * K + kt * 64 + (cb >> 1));
      *(u16x8*)(sB + row * 128 + (cb ^ ((row & 7) << 4))) = vb;
    }
    __syncthreads();
#pragma unroll
    for (int ks = 0; ks < 2; ++ks) {
      s16x8 af[4], bfr[4];
      int cb = ks * 64 + (l >> 4) * 16;
#pragma unroll
      for (int i = 0; i < 4; ++i) {
        int ra = wr * 64 + i * 16 + (l & 15);
        af[i] = *(const s16x8*)(sA + ra * 128 + (cb ^ ((ra & 7) << 4)));
        int rb = wc * 64 + i * 16 + (l & 15);
        bfr[i] = *(const s16x8*)(sB + rb * 128 + (cb ^ ((rb & 7) << 4)));
      }
#pragma unroll
      for (int i = 0; i < 4; ++i)
#pragma unroll
        for (int j = 0; j < 4; ++j)
          acc[i][j] = __builtin_amdgcn_mfma_f32_16x16x32_bf16(af[i], bfr[j], acc[i][j], 0, 0, 0);
    }
  }
#pragma unroll
  for (int i = 0; i < 4; ++i)
#pragma unroll
    for (int j = 0; j < 4; ++j)
#pragma unroll
      for (int r = 0; r < 4; ++r) {
        int row = m0 + wr * 64 + i * 16 + (l >> 4) * 4 + r;
        int col = n0 + wc * 64 + j * 16 + (l & 15);
        if constexpr (__is_same(OutT, float)) C[(size_t)row * N + col] = acc[i][j][r];
        else                                  C[(size_t)row * N + col] = f2bf(acc[i][j][r]);
      }
}

// ------- fused RMSNorm + RoPE; one wave per (row, head) vector -------
__global__ __launch_bounds__(256) void k_normrope(const u16* __restrict__ qkv, u16* __restrict__ qn,
                                                  u16* __restrict__ kn, const float* __restrict__ qs,
                                                  const float* __restrict__ ksc,
                                                  const float* __restrict__ cosb,
                                                  const float* __restrict__ sinb) {
  int j = blockIdx.x * 4 + (threadIdx.x >> 6);
  int l = threadIdx.x & 63;
  bool isQ = j < MROWS * 32;
  int m, head, incol;
  if (isQ) { m = j >> 5; head = j & 31; incol = head * 64; }
  else     { int j2 = j - MROWS * 32; m = j2 >> 3; head = j2 & 7; incol = 2048 + head * 64; }
  float v = bf2f(qkv[(size_t)m * NQKV + incol + l]);
  float ss = v * v;
#pragma unroll
  for (int off = 1; off < 64; off <<= 1) ss += __shfl_xor(ss, off, 64);
  float inv = rsqrtf(ss * (1.0f / 64.0f) + 1e-6f);
  float nx = v * inv * (isQ ? qs[l] : ksc[l]);
  int s = m & 2047;
  float c = cosb[s * 64 + l], sn = sinb[s * 64 + l];
  float partner = __shfl_xor(nx, 32, 64);
  float rot = (l < 32) ? -partner : partner;
  float outv = nx * c + rot * sn;
  if (isQ) {
    outv *= 0.125f;  // fold 1/sqrt(HD) into Q
    qn[(size_t)m * 2048 + incol + l] = f2bf(outv);
  } else {
    kn[(size_t)m * 512 + head * 64 + l] = f2bf(outv);
  }
}

// ------- V transpose: QKV v-region -> vt[(b*8+kv)*64 + d][s] -------
__global__ __launch_bounds__(256) void k_vtrans(const u16* __restrict__ qkv, u16* __restrict__ vt) {
  __shared__ u16 t[64][68];
  int s0 = blockIdx.x * 64;
  int bk = blockIdx.y;  // b*8 + kv
  int tid = threadIdx.x;
#pragma unroll
  for (int r = 0; r < 4; ++r) {
    int s = r * 16 + (tid >> 4);
    int d = (tid & 15) * 4;
    u16x4 v = *(const u16x4*)(qkv + (size_t)((bk >> 3) * 2048 + s0 + s) * NQKV + 2560 + (bk & 7) * 64 + d);
    t[d + 0][s] = v[0];
    t[d + 1][s] = v[1];
    t[d + 2][s] = v[2];
    t[d + 3][s] = v[3];
  }
  __syncthreads();
#pragma unroll
  for (int r = 0; r < 4; ++r) {
    int d = r * 16 + (tid >> 4);
    int sl = (tid & 15) * 4;
    u16x4 o = { t[d][sl], t[d][sl + 1], t[d][sl + 2], t[d][sl + 3] };
    *(u16x4*)(vt + (size_t)(bk * 64 + d) * 2048 + s0 + sl) = o;
  }
}

// ------- causal flash attention: block = (b, h, 128 q-rows), 4 waves x 32 rows -------
__global__ __launch_bounds__(256) void k_attn(const u16* __restrict__ qn, const u16* __restrict__ kn,
                                              const u16* __restrict__ vt, u16* __restrict__ aout) {
  __shared__ char sK[64 * 128];   // [key][d], swizzled
  __shared__ char sV[64 * 128];   // [d][key], swizzled
  __shared__ char sP[128 * 128];  // [block-local qrow][key], swizzled, per-wave regions
  int bid = blockIdx.x;
  int qb = bid & 15, h = (bid >> 4) & 31, b = bid >> 9;
  int kvh = h >> 2;
  int tid = threadIdx.x, l = tid & 63, w = tid >> 6;
  int q0 = qb * 128;
  s16x8 qf[2][2];
#pragma unroll
  for (int mf = 0; mf < 2; ++mf)
#pragma unroll
    for (int ks = 0; ks < 2; ++ks) {
      int qrow = q0 + w * 32 + mf * 16 + (l & 15);
      int col = h * 64 + ks * 32 + (l >> 4) * 8;
      qf[mf][ks] = *(const s16x8*)(qn + (size_t)(b * 2048 + qrow) * 2048 + col);
    }
  f32x4 O[2][4] = {};
  float mst[2][4], lst[2][4];
#pragma unroll
  for (int mf = 0; mf < 2; ++mf)
#pragma unroll
    for (int r = 0; r < 4; ++r) { mst[mf][r] = -1e30f; lst[mf][r] = 0.f; }
  int nkv = 2 * qb + 2;
  for (int t = 0; t < nkv; ++t) {
    int kv0 = t * 64;
    __syncthreads();
#pragma unroll
    for (int r = 0; r < 2; ++r) {
      int key = (tid >> 3) + r * 32;
      int d0 = (tid & 7) * 8;
      u16x8 v = *(const u16x8*)(kn + (size_t)(b * 2048 + kv0 + key) * 512 + kvh * 64 + d0);
      *(u16x8*)(sK + key * 128 + ((d0 * 2) ^ ((key & 7) << 4))) = v;
      u16x8 v2 = *(const u16x8*)(vt + (size_t)((b * 8 + kvh) * 64 + key) * 2048 + kv0 + d0);
      *(u16x8*)(sV + key * 128 + ((d0 * 2) ^ ((key & 7) << 4))) = v2;  // here key plays "d", d0 plays "key"
    }
    __syncthreads();
    f32x4 sc[2][4] = {};
#pragma unroll
    for (int ks = 0; ks < 2; ++ks) {
      s16x8 kf[4];
      int cb = ks * 64 + (l >> 4) * 16;
#pragma unroll
      for (int nf = 0; nf < 4; ++nf) {
        int key = nf * 16 + (l & 15);
        kf[nf] = *(const s16x8*)(sK + key * 128 + (cb ^ ((key & 7) << 4)));
      }
#pragma unroll
      for (int mf = 0; mf < 2; ++mf)
#pragma unroll
        for (int nf = 0; nf < 4; ++nf)
          sc[mf][nf] = __builtin_amdgcn_mfma_f32_16x16x32_bf16(qf[mf][ks], kf[nf], sc[mf][nf], 0, 0, 0);
    }
    // causal mask
#pragma unroll
    for (int mf = 0; mf < 2; ++mf)
#pragma unroll
      for (int nf = 0; nf < 4; ++nf)
#pragma unroll
        for (int r = 0; r < 4; ++r) {
          int qrow = q0 + w * 32 + mf * 16 + (l >> 4) * 4 + r;
          int key = kv0 + nf * 16 + (l & 15);
          if (key > qrow) sc[mf][nf][r] = -1e30f;
        }
    // online softmax update
#pragma unroll
    for (int mf = 0; mf < 2; ++mf) {
      float mx[4], alpha[4], rs[4];
#pragma unroll
      for (int r = 0; r < 4; ++r) {
        mx[r] = sc[mf][0][r];
#pragma unroll
        for (int nf = 1; nf < 4; ++nf) mx[r] = fmaxf(mx[r], sc[mf][nf][r]);
#pragma unroll
        for (int off = 1; off < 16; off <<= 1) mx[r] = fmaxf(mx[r], __shfl_xor(mx[r], off, 64));
        float mnew = fmaxf(mst[mf][r], mx[r]);
        alpha[r] = __expf(mst[mf][r] - mnew);
        mst[mf][r] = mnew;
        rs[r] = 0.f;
      }
#pragma unroll
      for (int nf = 0; nf < 4; ++nf)
#pragma unroll
        for (int r = 0; r < 4; ++r) {
          float p = __expf(sc[mf][nf][r] - mst[mf][r]);
          rs[r] += p;
          int row = w * 32 + mf * 16 + (l >> 4) * 4 + r;
          int kb = (nf * 16 + (l & 15)) * 2;
          *(u16*)(sP + row * 128 + (kb ^ ((row & 7) << 4))) = f2bf(p);
        }
#pragma unroll
      for (int r = 0; r < 4; ++r) {
#pragma unroll
        for (int off = 1; off < 16; off <<= 1) rs[r] += __shfl_xor(rs[r], off, 64);
        lst[mf][r] = lst[mf][r] * alpha[r] + rs[r];
      }
#pragma unroll
      for (int df = 0; df < 4; ++df)
#pragma unroll
        for (int r = 0; r < 4; ++r) O[mf][df][r] *= alpha[r];
    }
    __syncthreads();  // order sP writes before reads (and keep waves together)
    // PV
#pragma unroll
    for (int ks = 0; ks < 2; ++ks) {
      int cb = ks * 64 + (l >> 4) * 16;
      s16x8 pf[2], vf[4];
#pragma unroll
      for (int mf = 0; mf < 2; ++mf) {
        int row = w * 32 + mf * 16 + (l & 15);
        pf[mf] = *(const s16x8*)(sP + row * 128 + (cb ^ ((row & 7) << 4)));
      }
#pragma unroll
      for (int df = 0; df < 4; ++df) {
        int d = df * 16 + (l & 15);
        vf[df] = *(const s16x8*)(sV + d * 128 + (cb ^ ((d & 7) << 4)));
      }
#pragma unroll
      for (int mf = 0; mf < 2; ++mf)
#pragma unroll
        for (int df = 0; df < 4; ++df)
          O[mf][df] = __builtin_amdgcn_mfma_f32_16x16x32_bf16(pf[mf], vf[df], O[mf][df], 0, 0, 0);
    }
  }
#pragma unroll
  for (int mf = 0; mf < 2; ++mf)
#pragma unroll
    for (int df = 0; df < 4; ++df)
#pragma unroll
      for (int r = 0; r < 4; ++r) {
        int qrow = q0 + w * 32 + mf * 16 + (l >> 4) * 4 + r;
        int col = h * 64 + df * 16 + (l & 15);
        aout[(size_t)(b * 2048 + qrow) * 2048 + col] = f2bf(O[mf][df][r] / lst[mf][r]);
      }
}

extern "C" void kernel_launch(void* const* d_in, const int* in_sizes, int n_in,
                              void* d_out, int out_size, void* d_ws, size_t ws_size,
                              hipStream_t stream) {
  (void)in_sizes; (void)n_in; (void)out_size; (void)ws_size;
  const float* x    = (const float*)d_in[0];
  const float* wq   = (const float*)d_in[1];
  const float* wk   = (const float*)d_in[2];
  const float* wv   = (const float*)d_in[3];
  const float* wo   = (const float*)d_in[4];
  const float* qs   = (const float*)d_in[5];
  const float* ksc  = (const float*)d_in[6];
  const float* cosb = (const float*)d_in[7];
  const float* sinb = (const float*)d_in[8];
  float* out = (float*)d_out;
  char* ws = (char*)d_ws;
  // workspace layout (bytes): total ~100 MB
  u16* xbf   = (u16*)(ws);                 // 16 MB  4096x2048 bf16
  u16* wqkvt = (u16*)(ws + 16777216);      // 12 MB  3072x2048 bf16 (W^T)
  u16* wot   = (u16*)(ws + 29360128);      // 8 MB   2048x2048 bf16 (Wo^T)
  u16* qkv   = (u16*)(ws + 37748736);      // 24 MB  4096x3072 bf16
  u16* qn    = (u16*)(ws + 62914560);      // 16 MB  4096x2048 bf16
  u16* kn    = (u16*)(ws + 79691776);      // 4 MB   4096x512 bf16
  u16* vt    = (u16*)(ws + 83886080);      // 4 MB   (b,kv,d) x 2048 bf16
  u16* aout  = (u16*)(ws + 88080384);      // 16 MB  4096x2048 bf16

  k_conv_x<<<8192, 256, 0, stream>>>(x, xbf);
  k_transw<<<dim3(32, 32), 256, 0, stream>>>(wq, wqkvt, 2048, 2048);
  k_transw<<<dim3(8, 32), 256, 0, stream>>>(wk, wqkvt + (size_t)2048 * 2048, 512, 2048);
  k_transw<<<dim3(8, 32), 256, 0, stream>>>(wv, wqkvt + (size_t)2560 * 2048, 512, 2048);
  k_transw<<<dim3(32, 32), 256, 0, stream>>>(wo, wot, 2048, 2048);
  k_gemm<u16><<<dim3(NQKV / 128, MROWS / 128), 256, 0, stream>>>(xbf, wqkvt, qkv, MROWS, NQKV, 2048);
  k_normrope<<<40960, 256, 0, stream>>>(qkv, qn, kn, qs, ksc, cosb, sinb);
  k_vtrans<<<dim3(32, 16), 256, 0, stream>>>(qkv, vt);
  k_attn<<<1024, 256, 0, stream>>>(qn, kn, vt, aout);
  k_gemm<float><<<dim3(DMODEL / 128, MROWS / 128), 256, 0, stream>>>(aout, wot, out, MROWS, DMODEL, 2048);
}

// Round 2
// 275.985 us; speedup vs baseline: 1.4453x; 1.4453x over previous
//
#include <hip/hip_runtime.h>
#include <hip/hip_bf16.h>

typedef float f32x4 __attribute__((ext_vector_type(4)));
typedef short s16x8 __attribute__((ext_vector_type(8)));
typedef unsigned short u16;
typedef unsigned short u16x8 __attribute__((ext_vector_type(8)));
typedef unsigned short u16x4 __attribute__((ext_vector_type(4)));
typedef unsigned int u32;
typedef unsigned int u32x4 __attribute__((ext_vector_type(4)));

#define MROWS 4096   // B*S
#define NQKV  3072   // NH*HD + 2*NKV*HD
#define DMODEL 2048

__device__ __forceinline__ u16 f2bf(float f) {
  __hip_bfloat16 h = __float2bfloat16(f);
  return __builtin_bit_cast(u16, h);
}
__device__ __forceinline__ float bf2f(u16 u) {
  __hip_bfloat16 h = __builtin_bit_cast(__hip_bfloat16, u);
  return __bfloat162float(h);
}

// ---------------- fp32 -> bf16 convert (x) ----------------
__global__ __launch_bounds__(256) void k_conv_x(const float* __restrict__ x, u16* __restrict__ o) {
  size_t i = ((size_t)blockIdx.x * 256 + threadIdx.x) * 4;
  float4 v = *(const float4*)(x + i);
  u16x4 r = { f2bf(v.x), f2bf(v.y), f2bf(v.z), f2bf(v.w) };
  *(u16x4*)(o + i) = r;
}

// ------- transpose + convert: src (K x N) f32 -> dst (N x K) bf16 -------
__global__ __launch_bounds__(256) void k_transw(const float* __restrict__ src, u16* __restrict__ dst,
                                                int N, int K) {
  __shared__ u16 t[64][68];
  int n0 = blockIdx.x * 64, k0 = blockIdx.y * 64;
  int tid = threadIdx.x;
#pragma unroll
  for (int r = 0; r < 4; ++r) {
    int k = r * 16 + (tid >> 4);
    int n = (tid & 15) * 4;
    float4 v = *(const float4*)(src + (size_t)(k0 + k) * N + n0 + n);
    t[n + 0][k] = f2bf(v.x);
    t[n + 1][k] = f2bf(v.y);
    t[n + 2][k] = f2bf(v.z);
    t[n + 3][k] = f2bf(v.w);
  }
  __syncthreads();
#pragma unroll
  for (int r = 0; r < 4; ++r) {
    int n = r * 16 + (tid >> 4);
    int k = (tid & 15) * 4;
    u16x4 o = { t[n][k], t[n][k + 1], t[n][k + 2], t[n][k + 3] };
    *(u16x4*)(dst + (size_t)(n0 + n) * K + k0 + k) = o;
  }
}

// ---------------- bf16 GEMM: C(MxN) = A(MxK) * Bt(NxK)^T ----------------
template <typename OutT>
__global__ __launch_bounds__(256) void k_gemm(const u16* __restrict__ A, const u16* __restrict__ Bt,
                                              OutT* __restrict__ C, int M, int N, int K) {
  __shared__ char sA[128 * 128];
  __shared__ char sB[128 * 128];
  const int tid = threadIdx.x;
  const int l = tid & 63;
  const int m0 = blockIdx.y * 128, n0 = blockIdx.x * 128;
  const int wr = tid >> 7, wc = (tid >> 6) & 1;
  f32x4 acc[4][4] = {};
  const int nkt = K >> 6;
  for (int kt = 0; kt < nkt; ++kt) {
    __syncthreads();
#pragma unroll
    for (int c = 0; c < 4; ++c) {
      int p = c * 4096 + tid * 16;
      int row = p >> 7, cb = p & 127;
      u16x8 va = *(const u16x8*)(A + (size_t)(m0 + row) * K + kt * 64 + (cb >> 1));
      *(u16x8*)(sA + row * 128 + (cb ^ ((row & 7) << 4))) = va;
      u16x8 vb = *(const u16x8*)(Bt + (size_t)(n0 + row) * K + kt * 64 + (cb >> 1));
      *(u16x8*)(sB + row * 128 + (cb ^ ((row & 7) << 4))) = vb;
    }
    __syncthreads();
#pragma unroll
    for (int ks = 0; ks < 2; ++ks) {
      s16x8 af[4], bfr[4];
      int cb = ks * 64 + (l >> 4) * 16;
#pragma unroll
      for (int i = 0; i < 4; ++i) {
        int ra = wr * 64 + i * 16 + (l & 15);
        af[i] = *(const s16x8*)(sA + ra * 128 + (cb ^ ((ra & 7) << 4)));
        int rb = wc * 64 + i * 16 + (l & 15);
        bfr[i] = *(const s16x8*)(sB + rb * 128 + (cb ^ ((rb & 7) << 4)));
      }
#pragma unroll
      for (int i = 0; i < 4; ++i)
#pragma unroll
        for (int j = 0; j < 4; ++j)
          acc[i][j] = __builtin_amdgcn_mfma_f32_16x16x32_bf16(af[i], bfr[j], acc[i][j], 0, 0, 0);
    }
  }
#pragma unroll
  for (int i = 0; i < 4; ++i)
#pragma unroll
    for (int j = 0; j < 4; ++j)
#pragma unroll
      for (int r = 0; r < 4; ++r) {
        int row = m0 + wr * 64 + i * 16 + (l >> 4) * 4 + r;
        int col = n0 + wc * 64 + j * 16 + (l & 15);
        if constexpr (__is_same(OutT, float)) C[(size_t)row * N + col] = acc[i][j][r];
        else                                  C[(size_t)row * N + col] = f2bf(acc[i][j][r]);
      }
}

// ------- fused RMSNorm + RoPE; one wave per (row, head) vector -------
__global__ __launch_bounds__(256) void k_normrope(const u16* __restrict__ qkv, u16* __restrict__ qn,
                                                  u16* __restrict__ kn, const float* __restrict__ qs,
                                                  const float* __restrict__ ksc,
                                                  const float* __restrict__ cosb,
                                                  const float* __restrict__ sinb) {
  int j = blockIdx.x * 4 + (threadIdx.x >> 6);
  int l = threadIdx.x & 63;
  bool isQ = j < MROWS * 32;
  int m, head, incol;
  if (isQ) { m = j >> 5; head = j & 31; incol = head * 64; }
  else     { int j2 = j - MROWS * 32; m = j2 >> 3; head = j2 & 7; incol = 2048 + head * 64; }
  float v = bf2f(qkv[(size_t)m * NQKV + incol + l]);
  float ss = v * v;
#pragma unroll
  for (int off = 1; off < 64; off <<= 1) ss += __shfl_xor(ss, off, 64);
  float inv = rsqrtf(ss * (1.0f / 64.0f) + 1e-6f);
  float nx = v * inv * (isQ ? qs[l] : ksc[l]);
  int s = m & 2047;
  float c = cosb[s * 64 + l], sn = sinb[s * 64 + l];
  float partner = __shfl_xor(nx, 32, 64);
  float rot = (l < 32) ? -partner : partner;
  float outv = nx * c + rot * sn;
  if (isQ) {
    outv *= 0.125f;  // fold 1/sqrt(HD) into Q
    qn[(size_t)m * 2048 + incol + l] = f2bf(outv);
  } else {
    kn[(size_t)m * 512 + head * 64 + l] = f2bf(outv);
  }
}

// ------- V transpose: QKV v-region -> vt[(b*8+kv)*64 + d][s] -------
__global__ __launch_bounds__(256) void k_vtrans(const u16* __restrict__ qkv, u16* __restrict__ vt) {
  __shared__ u16 t[64][68];
  int s0 = blockIdx.x * 64;
  int bk = blockIdx.y;  // b*8 + kv
  int tid = threadIdx.x;
#pragma unroll
  for (int r = 0; r < 4; ++r) {
    int s = r * 16 + (tid >> 4);
    int d = (tid & 15) * 4;
    u16x4 v = *(const u16x4*)(qkv + (size_t)((bk >> 3) * 2048 + s0 + s) * NQKV + 2560 + (bk & 7) * 64 + d);
    t[d + 0][s] = v[0];
    t[d + 1][s] = v[1];
    t[d + 2][s] = v[2];
    t[d + 3][s] = v[3];
  }
  __syncthreads();
#pragma unroll
  for (int r = 0; r < 4; ++r) {
    int d = r * 16 + (tid >> 4);
    int sl = (tid & 15) * 4;
    u16x4 o = { t[d][sl], t[d][sl + 1], t[d][sl + 2], t[d][sl + 3] };
    *(u16x4*)(vt + (size_t)(bk * 64 + d) * 2048 + s0 + sl) = o;
  }
}

// ------- causal flash attention, swapped-operand form -------
// Block = (b,h, pair of q-tiles {31-p, p}) -> uniform 33 KV-tiles per block.
// 4 waves x 16 q-rows per q-tile (QBLK=64), KVBLK=64.
// QK^T: mfma(A=K, B=Q)  -> lane owns q = lane&15 -> lane-local softmax.
// PV:   mfma(A=V^T, B=P^T) -> O^T with q = lane&15 (lane-local rescale/div).
__global__ __launch_bounds__(256) void k_attn(const u16* __restrict__ qn, const u16* __restrict__ kn,
                                              const u16* __restrict__ vt, u16* __restrict__ aout) {
  __shared__ char sK[64 * 128];     // [key][d]  swizzled
  __shared__ char sV[64 * 128];     // [d][key]  swizzled
  __shared__ float sT[4 * 16 * 64]; // per-wave O-transpose buffer
  const int bid = blockIdx.x;
  const int p = bid >> 6;
  const int bh = bid & 63, b = bh >> 5, h = bh & 31;
  const int kvh = h >> 2;
  const int tid = threadIdx.x, l = tid & 63, w = tid >> 6;
  const int lo = l & 15, hi = l >> 4;
  for (int qi = 0; qi < 2; ++qi) {
    const int qt = qi ? p : 31 - p;   // big tile first
    const int q0w = qt * 64 + w * 16;
    s16x8 qf[2];
#pragma unroll
    for (int ks = 0; ks < 2; ++ks)
      qf[ks] = *(const s16x8*)(qn + (size_t)(b * 2048 + q0w + lo) * 2048 + h * 64 + ks * 32 + hi * 8);
    f32x4 O[4] = {};
    float mst = -1e30f, lst = 0.f;
    for (int t = 0; t <= qt; ++t) {
      const int kv0 = t * 64;
      __syncthreads();
      {
        const u16* ksrc = kn + (size_t)(b * 2048 + kv0) * 512 + kvh * 64;
        const u16* vsrc = vt + (size_t)((b * 8 + kvh) * 64) * 2048 + kv0;
#pragma unroll
        for (int r2 = 0; r2 < 2; ++r2) {
          int c = r2 * 256 + tid;
          int row = c >> 3, col = (c & 7) * 8;
          u16x8 kv_ = *(const u16x8*)(ksrc + (size_t)row * 512 + col);
          *(u16x8*)(sK + row * 128 + ((col * 2) ^ ((row & 7) << 4))) = kv_;
          u16x8 vv = *(const u16x8*)(vsrc + (size_t)row * 2048 + col);
          *(u16x8*)(sV + row * 128 + ((col * 2) ^ ((row & 7) << 4))) = vv;
        }
      }
      __syncthreads();
      // ---- QK^T (swapped): sc[nf] holds S[key=kv0+nf*16+hi*4+r][q=q0w+lo]
      f32x4 sc[4] = {};
#pragma unroll
      for (int ks = 0; ks < 2; ++ks) {
        int cb = ks * 64 + hi * 16;
#pragma unroll
        for (int nf = 0; nf < 4; ++nf) {
          int row = nf * 16 + lo;
          s16x8 kf = *(const s16x8*)(sK + row * 128 + (cb ^ ((row & 7) << 4)));
          sc[nf] = __builtin_amdgcn_mfma_f32_16x16x32_bf16(kf, qf[ks], sc[nf], 0, 0, 0);
        }
      }
      if (t == qt) {  // diagonal tile: causal mask
#pragma unroll
        for (int nf = 0; nf < 4; ++nf)
#pragma unroll
          for (int r = 0; r < 4; ++r)
            if (nf * 16 + hi * 4 + r > w * 16 + lo) sc[nf][r] = -1e30f;
      }
      // ---- lane-local online softmax (q = lo)
      float mloc = -1e30f;
#pragma unroll
      for (int nf = 0; nf < 4; ++nf)
#pragma unroll
        for (int r = 0; r < 4; ++r) mloc = fmaxf(mloc, sc[nf][r]);
      mloc = fmaxf(mloc, __shfl_xor(mloc, 16, 64));
      mloc = fmaxf(mloc, __shfl_xor(mloc, 32, 64));
      const float mnew = fmaxf(mst, mloc);
      const float alpha = __expf(mst - mnew);
      mst = mnew;
      float rs = 0.f;
      u32 pk[4][2];
#pragma unroll
      for (int nf = 0; nf < 4; ++nf) {
        float p0 = __expf(sc[nf][0] - mnew);
        float p1 = __expf(sc[nf][1] - mnew);
        float p2 = __expf(sc[nf][2] - mnew);
        float p3 = __expf(sc[nf][3] - mnew);
        rs += (p0 + p1) + (p2 + p3);
        pk[nf][0] = (u32)f2bf(p0) | ((u32)f2bf(p1) << 16);
        pk[nf][1] = (u32)f2bf(p2) | ((u32)f2bf(p3) << 16);
      }
      rs += __shfl_xor(rs, 16, 64);
      rs += __shfl_xor(rs, 32, 64);
      lst = lst * alpha + rs;
#pragma unroll
      for (int df = 0; df < 4; ++df)
#pragma unroll
        for (int r = 0; r < 4; ++r) O[df][r] *= alpha;
      // ---- redistribute P^T pairs into B-fragment layout + PV
#pragma unroll
      for (int ks = 0; ks < 2; ++ks) {
        u32 wds[4];
#pragma unroll
        for (int m = 0; m < 4; ++m) {
          int src = lo | ((((hi & 1) * 2 + (m >> 1)) & 3) << 4);
          u32 a0 = (u32)__shfl((int)pk[2 * ks][m & 1], src, 64);
          u32 a1 = (u32)__shfl((int)pk[2 * ks + 1][m & 1], src, 64);
          wds[m] = (hi & 2) ? a1 : a0;
        }
        u32x4 wv = { wds[0], wds[1], wds[2], wds[3] };
        s16x8 pb = __builtin_bit_cast(s16x8, wv);
        int cb = ks * 64 + hi * 16;
#pragma unroll
        for (int df = 0; df < 4; ++df) {
          int row = df * 16 + lo;
          s16x8 vf = *(const s16x8*)(sV + row * 128 + (cb ^ ((row & 7) << 4)));
          O[df] = __builtin_amdgcn_mfma_f32_16x16x32_bf16(vf, pb, O[df], 0, 0, 0);
        }
      }
    }
    // ---- epilogue: O^T (q=lo, d=df*16+hi*4+r) -> LDS transpose -> coalesced store
    const float inv = 1.0f / lst;
    float* tw = sT + w * 1024;
#pragma unroll
    for (int df = 0; df < 4; ++df)
#pragma unroll
      for (int r = 0; r < 4; ++r) {
        int d = df * 16 + hi * 4 + r;
        tw[lo * 64 + (d ^ ((lo & 7) << 2))] = O[df][r] * inv;
      }
    const int qrow = l >> 2, d0 = (l & 3) * 16;
#pragma unroll
    for (int j = 0; j < 4; ++j) {
      f32x4 v = *(const f32x4*)(tw + qrow * 64 + ((d0 + 4 * j) ^ ((qrow & 7) << 2)));
      u16x4 o = { f2bf(v[0]), f2bf(v[1]), f2bf(v[2]), f2bf(v[3]) };
      *(u16x4*)(aout + (size_t)(b * 2048 + qt * 64 + w * 16 + qrow) * 2048 + h * 64 + d0 + 4 * j) = o;
    }
  }
}

extern "C" void kernel_launch(void* const* d_in, const int* in_sizes, int n_in,
                              void* d_out, int out_size, void* d_ws, size_t ws_size,
                              hipStream_t stream) {
  (void)in_sizes; (void)n_in; (void)out_size; (void)ws_size;
  const float* x    = (const float*)d_in[0];
  const float* wq   = (const float*)d_in[1];
  const float* wk   = (const float*)d_in[2];
  const float* wv   = (const float*)d_in[3];
  const float* wo   = (const float*)d_in[4];
  const float* qs   = (const float*)d_in[5];
  const float* ksc  = (const float*)d_in[6];
  const float* cosb = (const float*)d_in[7];
  const float* sinb = (const float*)d_in[8];
  float* out = (float*)d_out;
  char* ws = (char*)d_ws;
  u16* xbf   = (u16*)(ws);                 // 16 MB  4096x2048 bf16
  u16* wqkvt = (u16*)(ws + 16777216);      // 12 MB  3072x2048 bf16 (W^T)
  u16* wot   = (u16*)(ws + 29360128);      // 8 MB   2048x2048 bf16 (Wo^T)
  u16* qkv   = (u16*)(ws + 37748736);      // 24 MB  4096x3072 bf16
  u16* qn    = (u16*)(ws + 62914560);      // 16 MB  4096x2048 bf16
  u16* kn    = (u16*)(ws + 79691776);      // 4 MB   4096x512 bf16
  u16* vt    = (u16*)(ws + 83886080);      // 4 MB   (b,kv,d) x 2048 bf16
  u16* aout  = (u16*)(ws + 88080384);      // 16 MB  4096x2048 bf16

  k_conv_x<<<8192, 256, 0, stream>>>(x, xbf);
  k_transw<<<dim3(32, 32), 256, 0, stream>>>(wq, wqkvt, 2048, 2048);
  k_transw<<<dim3(8, 32), 256, 0, stream>>>(wk, wqkvt + (size_t)2048 * 2048, 512, 2048);
  k_transw<<<dim3(8, 32), 256, 0, stream>>>(wv, wqkvt + (size_t)2560 * 2048, 512, 2048);
  k_transw<<<dim3(32, 32), 256, 0, stream>>>(wo, wot, 2048, 2048);
  k_gemm<u16><<<dim3(NQKV / 128, MROWS / 128), 256, 0, stream>>>(xbf, wqkvt, qkv, MROWS, NQKV, 2048);
  k_normrope<<<40960, 256, 0, stream>>>(qkv, qn, kn, qs, ksc, cosb, sinb);
  k_vtrans<<<dim3(32, 16), 256, 0, stream>>>(qkv, vt);
  k_attn<<<1024, 256, 0, stream>>>(qn, kn, vt, aout);
  k_gemm<float><<<dim3(DMODEL / 128, MROWS / 128), 256, 0, stream>>>(aout, wot, out, MROWS, DMODEL, 2048);
}

// Round 4
// 268.206 us; speedup vs baseline: 1.4872x; 1.0290x over previous
//
#include <hip/hip_runtime.h>
#include <hip/hip_bf16.h>

typedef float f32x4 __attribute__((ext_vector_type(4)));
typedef float f32x16 __attribute__((ext_vector_type(16)));
typedef short s16x8 __attribute__((ext_vector_type(8)));
typedef unsigned short u16;
typedef unsigned short u16x8 __attribute__((ext_vector_type(8)));
typedef unsigned short u16x4 __attribute__((ext_vector_type(4)));
typedef unsigned int u32;
typedef unsigned int u32x4 __attribute__((ext_vector_type(4)));

#define MROWS 4096   // B*S
#define NQKV  3072   // NH*HD + 2*NKV*HD
#define DMODEL 2048

#define EXP2(x) __builtin_amdgcn_exp2f(x)

__device__ __forceinline__ u16 f2bf(float f) {
  __hip_bfloat16 h = __float2bfloat16(f);
  return __builtin_bit_cast(u16, h);
}
__device__ __forceinline__ float bf2f(u16 u) {
  __hip_bfloat16 h = __builtin_bit_cast(__hip_bfloat16, u);
  return __bfloat162float(h);
}

typedef __attribute__((address_space(3))) unsigned int lds_u32_t;
typedef const __attribute__((address_space(1))) unsigned int glb_u32_t;
__device__ __forceinline__ void gload_lds16(const void* g, void* l) {
  __builtin_amdgcn_global_load_lds((glb_u32_t*)g, (lds_u32_t*)l, 16, 0, 0);
}

// ---------------- fp32 -> bf16 convert (x) ----------------
__global__ __launch_bounds__(256) void k_conv_x(const float* __restrict__ x, u16* __restrict__ o) {
  size_t i = ((size_t)blockIdx.x * 256 + threadIdx.x) * 4;
  float4 v = *(const float4*)(x + i);
  u16x4 r = { f2bf(v.x), f2bf(v.y), f2bf(v.z), f2bf(v.w) };
  *(u16x4*)(o + i) = r;
}

// ------- transpose + convert: src (K x N) f32 -> dst (N x K) bf16 -------
__global__ __launch_bounds__(256) void k_transw(const float* __restrict__ src, u16* __restrict__ dst,
                                                int N, int K) {
  __shared__ u16 t[64][68];
  int n0 = blockIdx.x * 64, k0 = blockIdx.y * 64;
  int tid = threadIdx.x;
#pragma unroll
  for (int r = 0; r < 4; ++r) {
    int k = r * 16 + (tid >> 4);
    int n = (tid & 15) * 4;
    float4 v = *(const float4*)(src + (size_t)(k0 + k) * N + n0 + n);
    t[n + 0][k] = f2bf(v.x);
    t[n + 1][k] = f2bf(v.y);
    t[n + 2][k] = f2bf(v.z);
    t[n + 3][k] = f2bf(v.w);
  }
  __syncthreads();
#pragma unroll
  for (int r = 0; r < 4; ++r) {
    int n = r * 16 + (tid >> 4);
    int k = (tid & 15) * 4;
    u16x4 o = { t[n][k], t[n][k + 1], t[n][k + 2], t[n][k + 3] };
    *(u16x4*)(dst + (size_t)(n0 + n) * K + k0 + k) = o;
  }
}

// ------ bf16 GEMM, m97-style: global_load_lds staging, linear LDS, 128x128, BK=64 ------
template <typename OutT>
__global__ __launch_bounds__(256) void k_gemm(const u16* __restrict__ A, const u16* __restrict__ Bt,
                                              OutT* __restrict__ C, int M, int N, int K) {
  __shared__ u16 sA[128 * 64];
  __shared__ u16 sB[128 * 64];
  const int tid = threadIdx.x;
  const int l = tid & 63, wv = tid >> 6;
  const int lo = l & 15, hi = l >> 4;
  const int m0 = blockIdx.y * 128, n0 = blockIdx.x * 128;
  const int wr = tid >> 7, wc = (tid >> 6) & 1;
  f32x4 acc[4][4] = {};
  const int nkt = K >> 6;
  for (int kt = 0; kt < nkt; ++kt) {
    __syncthreads();
#pragma unroll
    for (int i = 0; i < 4; ++i) {
      int off = i * 2048 + wv * 512 + l * 8;  // element offset in LDS tile
      int row = off >> 6, col = off & 63;
      gload_lds16(A + (size_t)(m0 + row) * K + kt * 64 + col, &sA[off]);
      gload_lds16(Bt + (size_t)(n0 + row) * K + kt * 64 + col, &sB[off]);
    }
    __syncthreads();
#pragma unroll
    for (int ks = 0; ks < 2; ++ks) {
      s16x8 af4[4], bf4[4];
      const int ce = ks * 32 + hi * 8;
#pragma unroll
      for (int i = 0; i < 4; ++i) {
        af4[i] = *(const s16x8*)(&sA[(wr * 64 + i * 16 + lo) * 64 + ce]);
        bf4[i] = *(const s16x8*)(&sB[(wc * 64 + i * 16 + lo) * 64 + ce]);
      }
#pragma unroll
      for (int i = 0; i < 4; ++i)
#pragma unroll
        for (int j = 0; j < 4; ++j)
          acc[i][j] = __builtin_amdgcn_mfma_f32_16x16x32_bf16(af4[i], bf4[j], acc[i][j], 0, 0, 0);
    }
  }
#pragma unroll
  for (int i = 0; i < 4; ++i)
#pragma unroll
    for (int j = 0; j < 4; ++j)
#pragma unroll
      for (int r = 0; r < 4; ++r) {
        int row = m0 + wr * 64 + i * 16 + hi * 4 + r;
        int col = n0 + wc * 64 + j * 16 + lo;
        if constexpr (__is_same(OutT, float)) C[(size_t)row * N + col] = acc[i][j][r];
        else                                  C[(size_t)row * N + col] = f2bf(acc[i][j][r]);
      }
}

// ------- fused RMSNorm + RoPE; one wave per (row, head) vector -------
__global__ __launch_bounds__(256) void k_normrope(const u16* __restrict__ qkv, u16* __restrict__ qn,
                                                  u16* __restrict__ kn, const float* __restrict__ qs,
                                                  const float* __restrict__ ksc,
                                                  const float* __restrict__ cosb,
                                                  const float* __restrict__ sinb) {
  int j = blockIdx.x * 4 + (threadIdx.x >> 6);
  int l = threadIdx.x & 63;
  bool isQ = j < MROWS * 32;
  int m, head, incol;
  if (isQ) { m = j >> 5; head = j & 31; incol = head * 64; }
  else     { int j2 = j - MROWS * 32; m = j2 >> 3; head = j2 & 7; incol = 2048 + head * 64; }
  float v = bf2f(qkv[(size_t)m * NQKV + incol + l]);
  float ss = v * v;
#pragma unroll
  for (int off = 1; off < 64; off <<= 1) ss += __shfl_xor(ss, off, 64);
  float inv = rsqrtf(ss * (1.0f / 64.0f) + 1e-6f);
  float nx = v * inv * (isQ ? qs[l] : ksc[l]);
  int s = m & 2047;
  float c = cosb[s * 64 + l], sn = sinb[s * 64 + l];
  float partner = __shfl_xor(nx, 32, 64);
  float rot = (l < 32) ? -partner : partner;
  float outv = nx * c + rot * sn;
  if (isQ) {
    outv *= 0.125f * 1.44269504088896f;  // fold 1/sqrt(HD) and log2(e) into Q
    qn[(size_t)m * 2048 + incol + l] = f2bf(outv);
  } else {
    kn[(size_t)m * 512 + head * 64 + l] = f2bf(outv);
  }
}

// ------- V transpose: QKV v-region -> vt[(b*8+kv)*64 + d][s] -------
__global__ __launch_bounds__(256) void k_vtrans(const u16* __restrict__ qkv, u16* __restrict__ vt) {
  __shared__ u16 t[64][68];
  int s0 = blockIdx.x * 64;
  int bk = blockIdx.y;  // b*8 + kv
  int tid = threadIdx.x;
#pragma unroll
  for (int r = 0; r < 4; ++r) {
    int s = r * 16 + (tid >> 4);
    int d = (tid & 15) * 4;
    u16x4 v = *(const u16x4*)(qkv + (size_t)((bk >> 3) * 2048 + s0 + s) * NQKV + 2560 + (bk & 7) * 64 + d);
    t[d + 0][s] = v[0];
    t[d + 1][s] = v[1];
    t[d + 2][s] = v[2];
    t[d + 3][s] = v[3];
  }
  __syncthreads();
#pragma unroll
  for (int r = 0; r < 4; ++r) {
    int d = r * 16 + (tid >> 4);
    int sl = (tid & 15) * 4;
    u16x4 o = { t[d][sl], t[d][sl + 1], t[d][sl + 2], t[d][sl + 3] };
    *(u16x4*)(vt + (size_t)(bk * 64 + d) * 2048 + s0 + sl) = o;
  }
}

// ------- causal flash attention v3: 32x32 MFMA, dbuf K/V, 1 barrier/tile -------
// Block = (b,h, paired q-tiles {15-p, p} of 128 rows) -> uniform 34 KV-iters.
// 4 waves x 32 q-rows. QK^T swapped: mfma32(K, Q) -> lane owns q = l&31.
// PV swapped: mfma32(V^T, P^T) -> O^T, q stays lane-local.
__global__ __launch_bounds__(256) void k_attn(const u16* __restrict__ qn, const u16* __restrict__ kn,
                                              const u16* __restrict__ vt, u16* __restrict__ aout) {
  __shared__ char sK[2][64 * 128];  // [key][d] swizzled
  __shared__ char sV[2][64 * 128];  // [d][key] swizzled
  // XCD-friendly decode: blocks sharing (b,kvh) -> same bid%8 bucket
  const int bid = blockIdx.x;           // 512 blocks
  const int xcd = bid & 7, jj = bid >> 3;
  const int bkv = xcd | ((jj & 1) << 3);        // b*8+kvh, 0..15
  const int hsub = (jj >> 1) & 3, p = jj >> 3;  // 0..3, 0..7
  const int b = bkv >> 3, kvh = bkv & 7, h = kvh * 4 + hsub;
  const int tid = threadIdx.x, l = tid & 63, w = tid >> 6;
  const int l31 = l & 31, l5 = l >> 5;
  const int qtA = 15 - p, qtB = p;
  const int nA = 2 * qtA + 2;  // + nB = 2*qtB+2 -> total 34
  const u16* kbase = kn + (size_t)(b * 2048) * 512 + kvh * 64;
  const u16* vbase = vt + (size_t)((b * 8 + kvh) * 64) * 2048;
  const int srow = tid >> 3;        // 0..31
  const int scol = (tid & 7) * 8;   // 0..56

  u16x8 krg0, krg1, vrg0, vrg1;
  auto issue = [&](int kv0) {
    krg0 = *(const u16x8*)(kbase + (size_t)(kv0 + srow) * 512 + scol);
    krg1 = *(const u16x8*)(kbase + (size_t)(kv0 + srow + 32) * 512 + scol);
    vrg0 = *(const u16x8*)(vbase + (size_t)srow * 2048 + kv0 + scol);
    vrg1 = *(const u16x8*)(vbase + (size_t)(srow + 32) * 2048 + kv0 + scol);
  };
  auto stash = [&](int buf) {
    const int cb = scol * 2;
    const int r0 = srow, r1 = srow + 32;
    *(u16x8*)(sK[buf] + r0 * 128 + (cb ^ ((r0 & 7) << 4))) = krg0;
    *(u16x8*)(sK[buf] + r1 * 128 + (cb ^ ((r1 & 7) << 4))) = krg1;
    *(u16x8*)(sV[buf] + r0 * 128 + (cb ^ ((r0 & 7) << 4))) = vrg0;
    *(u16x8*)(sV[buf] + r1 * 128 + (cb ^ ((r1 & 7) << 4))) = vrg1;
  };

  s16x8 qf[4];
  f32x16 O0, O1;
  float mst, lst;
  auto loadQ = [&](int qt_) {
    const u16* qp = qn + (size_t)(b * 2048 + qt_ * 128 + w * 32 + l31) * 2048 + h * 64 + l5 * 8;
#pragma unroll
    for (int ki = 0; ki < 4; ++ki) qf[ki] = *(const s16x8*)(qp + ki * 16);
#pragma unroll
    for (int r = 0; r < 16; ++r) { O0[r] = 0.f; O1[r] = 0.f; }
    mst = -1e30f; lst = 0.f;
  };
  auto epi = [&](int qt_) {
    const float inv = 1.0f / lst;
    const size_t rowoff = (size_t)(b * 2048 + qt_ * 128 + w * 32 + l31) * 2048 + h * 64;
#pragma unroll
    for (int g = 0; g < 4; ++g) {
      const int d0 = 8 * g + 4 * l5;
      u16x4 o0 = { f2bf(O0[4*g+0]*inv), f2bf(O0[4*g+1]*inv), f2bf(O0[4*g+2]*inv), f2bf(O0[4*g+3]*inv) };
      *(u16x4*)(aout + rowoff + d0) = o0;
      u16x4 o1 = { f2bf(O1[4*g+0]*inv), f2bf(O1[4*g+1]*inv), f2bf(O1[4*g+2]*inv), f2bf(O1[4*g+3]*inv) };
      *(u16x4*)(aout + rowoff + 32 + d0) = o1;
    }
  };

  loadQ(qtA);
  issue(0);
  stash(0);
  for (int s = 0; s < 34; ++s) {
    const int cur = s & 1;
    __syncthreads();
    const int qt = (s < nA) ? qtA : qtB;
    const int kvt = (s < nA) ? s : s - nA;
    if (s + 1 < 34) {
      const int kn2 = (s + 1 < nA) ? s + 1 : s + 1 - nA;
      issue(kn2 * 64);
    }
    // ---- QK^T
    f32x16 sc0, sc1;
#pragma unroll
    for (int r = 0; r < 16; ++r) { sc0[r] = 0.f; sc1[r] = 0.f; }
#pragma unroll
    for (int ki = 0; ki < 4; ++ki) {
      const int cb = ki * 32 + l5 * 16;
      const int r0 = l31, r1 = 32 + l31;
      s16x8 a0 = *(const s16x8*)(sK[cur] + r0 * 128 + (cb ^ ((r0 & 7) << 4)));
      s16x8 a1 = *(const s16x8*)(sK[cur] + r1 * 128 + (cb ^ ((r1 & 7) << 4)));
      sc0 = __builtin_amdgcn_mfma_f32_32x32x16_bf16(a0, qf[ki], sc0, 0, 0, 0);
      sc1 = __builtin_amdgcn_mfma_f32_32x32x16_bf16(a1, qf[ki], sc1, 0, 0, 0);
    }
    // ---- causal mask (only near-diagonal tiles)
    if (kvt >= 2 * qt) {
      const int qrow = qt * 128 + w * 32 + l31;
      const int kb0 = kvt * 64;
#pragma unroll
      for (int r = 0; r < 16; ++r) {
        const int krow = (r & 3) + 8 * (r >> 2) + 4 * l5;
        if (kb0 + krow > qrow) sc0[r] = -1e30f;
        if (kb0 + 32 + krow > qrow) sc1[r] = -1e30f;
      }
    }
    // ---- lane-local online softmax (q = l31), exp2 domain
    float mloc = -1e30f;
#pragma unroll
    for (int r = 0; r < 16; ++r) { mloc = fmaxf(mloc, sc0[r]); mloc = fmaxf(mloc, sc1[r]); }
    mloc = fmaxf(mloc, __shfl_xor(mloc, 32, 64));
    const float mnew = fmaxf(mst, mloc);
    const float alpha = EXP2(mst - mnew);
    mst = mnew;
    float rs = 0.f;
    u32 pk0[4][2], pk1[4][2];
#pragma unroll
    for (int g = 0; g < 4; ++g) {
      float a0 = EXP2(sc0[4*g+0] - mnew), a1 = EXP2(sc0[4*g+1] - mnew);
      float a2 = EXP2(sc0[4*g+2] - mnew), a3 = EXP2(sc0[4*g+3] - mnew);
      float b0 = EXP2(sc1[4*g+0] - mnew), b1 = EXP2(sc1[4*g+1] - mnew);
      float b2 = EXP2(sc1[4*g+2] - mnew), b3 = EXP2(sc1[4*g+3] - mnew);
      rs += ((a0 + a1) + (a2 + a3)) + ((b0 + b1) + (b2 + b3));
      pk0[g][0] = (u32)f2bf(a0) | ((u32)f2bf(a1) << 16);
      pk0[g][1] = (u32)f2bf(a2) | ((u32)f2bf(a3) << 16);
      pk1[g][0] = (u32)f2bf(b0) | ((u32)f2bf(b1) << 16);
      pk1[g][1] = (u32)f2bf(b2) | ((u32)f2bf(b3) << 16);
    }
    rs += __shfl_xor(rs, 32, 64);
    lst = lst * alpha + rs;
#pragma unroll
    for (int r = 0; r < 16; ++r) { O0[r] *= alpha; O1[r] *= alpha; }
    // ---- PV: redistribute P^T words via one half-wave swap per k-step
#define PV_STEP(PK, H2, KB)                                                   \
    {                                                                         \
      u32 A0 = PK[2*(H2)][0], A1 = PK[2*(H2)][1];                             \
      u32 B0 = PK[2*(H2)+1][0], B1 = PK[2*(H2)+1][1];                         \
      u32 s0 = l5 ? A0 : B0, s1 = l5 ? A1 : B1;                               \
      u32 rc0 = (u32)__shfl_xor((int)s0, 32, 64);                             \
      u32 rc1 = (u32)__shfl_xor((int)s1, 32, 64);                             \
      u32 w0 = l5 ? rc0 : A0, w1 = l5 ? rc1 : A1;                             \
      u32 w2 = l5 ? B0 : rc0, w3 = l5 ? B1 : rc1;                             \
      u32x4 wv_ = { w0, w1, w2, w3 };                                         \
      s16x8 pb = __builtin_bit_cast(s16x8, wv_);                              \
      const int cb = (KB) * 32 + l5 * 16;                                     \
      const int rv0 = l31, rv1 = 32 + l31;                                    \
      s16x8 v0 = *(const s16x8*)(sV[cur] + rv0 * 128 + (cb ^ ((rv0 & 7) << 4))); \
      s16x8 v1 = *(const s16x8*)(sV[cur] + rv1 * 128 + (cb ^ ((rv1 & 7) << 4))); \
      O0 = __builtin_amdgcn_mfma_f32_32x32x16_bf16(v0, pb, O0, 0, 0, 0);      \
      O1 = __builtin_amdgcn_mfma_f32_32x32x16_bf16(v1, pb, O1, 0, 0, 0);      \
    }
    PV_STEP(pk0, 0, 0)
    PV_STEP(pk0, 1, 1)
    PV_STEP(pk1, 0, 2)
    PV_STEP(pk1, 1, 3)
#undef PV_STEP
    if (s + 1 < 34) stash(cur ^ 1);
    if (s == nA - 1) { epi(qtA); loadQ(qtB); }
    else if (s == 33) epi(qtB);
  }
}

extern "C" void kernel_launch(void* const* d_in, const int* in_sizes, int n_in,
                              void* d_out, int out_size, void* d_ws, size_t ws_size,
                              hipStream_t stream) {
  (void)in_sizes; (void)n_in; (void)out_size; (void)ws_size;
  const float* x    = (const float*)d_in[0];
  const float* wq   = (const float*)d_in[1];
  const float* wk   = (const float*)d_in[2];
  const float* wv   = (const float*)d_in[3];
  const float* wo   = (const float*)d_in[4];
  const float* qs   = (const float*)d_in[5];
  const float* ksc  = (const float*)d_in[6];
  const float* cosb = (const float*)d_in[7];
  const float* sinb = (const float*)d_in[8];
  float* out = (float*)d_out;
  char* ws = (char*)d_ws;
  u16* xbf   = (u16*)(ws);                 // 16 MB  4096x2048 bf16
  u16* wqkvt = (u16*)(ws + 16777216);      // 12 MB  3072x2048 bf16 (W^T)
  u16* wot   = (u16*)(ws + 29360128);      // 8 MB   2048x2048 bf16 (Wo^T)
  u16* qkv   = (u16*)(ws + 37748736);      // 24 MB  4096x3072 bf16
  u16* qn    = (u16*)(ws + 62914560);      // 16 MB  4096x2048 bf16
  u16* kn    = (u16*)(ws + 79691776);      // 4 MB   4096x512 bf16
  u16* vt    = (u16*)(ws + 83886080);      // 4 MB   (b,kv,d) x 2048 bf16
  u16* aout  = (u16*)(ws + 88080384);      // 16 MB  4096x2048 bf16

  k_conv_x<<<8192, 256, 0, stream>>>(x, xbf);
  k_transw<<<dim3(32, 32), 256, 0, stream>>>(wq, wqkvt, 2048, 2048);
  k_transw<<<dim3(8, 32), 256, 0, stream>>>(wk, wqkvt + (size_t)2048 * 2048, 512, 2048);
  k_transw<<<dim3(8, 32), 256, 0, stream>>>(wv, wqkvt + (size_t)2560 * 2048, 512, 2048);
  k_transw<<<dim3(32, 32), 256, 0, stream>>>(wo, wot, 2048, 2048);
  k_gemm<u16><<<dim3(NQKV / 128, MROWS / 128), 256, 0, stream>>>(xbf, wqkvt, qkv, MROWS, NQKV, 2048);
  k_normrope<<<40960, 256, 0, stream>>>(qkv, qn, kn, qs, ksc, cosb, sinb);
  k_vtrans<<<dim3(32, 16), 256, 0, stream>>>(qkv, vt);
  k_attn<<<512, 256, 0, stream>>>(qn, kn, vt, aout);
  k_gemm<float><<<dim3(DMODEL / 128, MROWS / 128), 256, 0, stream>>>(aout, wot, out, MROWS, DMODEL, 2048);
}